// Round 12
// baseline (1164.603 us; speedup 1.0000x reference)
//
#include <hip/hip_runtime.h>
#include <math.h>

#define B_   2048
#define T_   512
#define D_   8
#define H_   80
#define NB   16
#define NPAIR (B_ / NB)    // 128 pairs -> grid 256 (even=L0 producer, odd=L1 consumer)
#define NTH  320           // 5 waves
#define KS0  3             // A0: K=96  = [x_hi(8) | x_lo(8) | h0(80)]
#define KS1  5             // A1: K=160 = [h0(80) | h1(80)]
#define A0S  256
#define A1S  384
#define A0BUF (16 * A0S)   // 4 KB
#define A1BUF (16 * A1S)   // 6 KB
#define RING_D 16
#define RSLOT  2560        // 16 seq x 80 units x 2B
#define LOG2E 1.44269504f
#define K2    2.88539008f  // 2*log2(e)

typedef float f32x4  __attribute__((ext_vector_type(4)));
typedef short bf16x8 __attribute__((ext_vector_type(8)));
typedef unsigned short u16x4 __attribute__((ext_vector_type(4)));
typedef unsigned long long u64;

__device__ __forceinline__ float E2(float x) {
#if __has_builtin(__builtin_amdgcn_exp2f)
  return __builtin_amdgcn_exp2f(x);
#else
  return __expf(x * 0.6931471806f);
#endif
}
__device__ __forceinline__ unsigned short f2bf(float f) {  // RNE f32->bf16
  unsigned u = __builtin_bit_cast(unsigned, f);
  return (unsigned short)((u + 0x7FFFu + ((u >> 16) & 1u)) >> 16);
}
__device__ __forceinline__ float bf2f(unsigned short b) {
  unsigned u = ((unsigned)b) << 16;
  return __builtin_bit_cast(float, u);
}
__device__ __forceinline__ int swz(int row, int byte_in_row) {
  return byte_in_row ^ ((row & 7) << 4);
}
// LSTM cell, gates PRESCALED (i,f,o by log2e; g by 2*log2e). 7 trans ops.
__device__ __forceinline__ float cell(float ai, float af, float ag, float ao,
                                      float& c) {
  const float ei = E2(-ai), ef = E2(-af), eg = E2(-ag), eo = E2(-ao);
  const float P  = (1.0f + ei) * (1.0f + eg);
  const float pf = 1.0f + ef;
  const float cn = __builtin_fmaf(c, P, (1.0f - eg) * pf)
                 * __builtin_amdgcn_rcpf(P * pf);
  c = cn;
  const float ec = E2(-K2 * fabsf(cn));
  const float t  = (1.0f - ec)
                 * __builtin_amdgcn_rcpf((1.0f + eo) * (1.0f + ec));
  return copysignf(t, cn);
}

// ---- counting sort by length (DESCENDING) + zero the pair flags ----
__global__ __launch_bounds__(512)
void sort_by_len(const int* __restrict__ slen, int* __restrict__ perm,
                 int* __restrict__ flags) {   // flags = prog0[128] ++ prog1[128]
  __shared__ int cnt[513];
  const int tid = threadIdx.x;
  if (tid < 256) flags[tid] = 0;
  for (int i = tid; i < 513; i += 512) cnt[i] = 0;
  __syncthreads();
  for (int b = tid; b < B_; b += 512) atomicAdd(&cnt[T_ - slen[b]], 1);
  __syncthreads();
  if (tid == 0) { int s = 0;
    for (int k = 0; k < 513; ++k) { int c = cnt[k]; cnt[k] = s; s += c; } }
  __syncthreads();
  for (int b = tid; b < B_; b += 512) {
    int pos = atomicAdd(&cnt[T_ - slen[b]], 1);
    perm[pos] = b;
  }
}

// ---- producer/consumer pair kernel ----
// pair p = bid>>1; role = bid&1. role 0: layer-0 recurrence only, publishes
// h0(i) bf16 into global ring slot i%16 + release-counter prog0[p]=i (top of
// step i covers h0(0..i-1); final publish = mlen). role 1: layer-1 recurrence,
// acquires prog0 (chunk of 4, demand lead 5), prefetches ring slot i+1 into
// regs during step i (T14), publishes prog1 (flow control, lead window <=15).
// Deadlock-free: L0 stalls only if L1 > 10 behind; L1 stalls only if L0 < 5
// ahead -> mutually exclusive. All math identical to the fused R11 kernel.
__global__ __launch_bounds__(NTH)
void lstm2_pc(const float* __restrict__ X,
              const float* __restrict__ Wih0, const float* __restrict__ Whh0,
              const float* __restrict__ bih0, const float* __restrict__ bhh0,
              const float* __restrict__ Wih1, const float* __restrict__ Whh1,
              const float* __restrict__ bih1, const float* __restrict__ bhh1,
              const int* __restrict__ slen, const int* __restrict__ perm,
              int* __restrict__ prog0, int* __restrict__ prog1,
              char* __restrict__ ring, float* __restrict__ out)
{
  __shared__ char lds[2 * A1BUF];     // 12 KB (L0 uses first 8 KB as A0 dbuf)
  __shared__ int  pbs[NB], lns[NB];

  const int tid = threadIdx.x;
  const int w   = tid >> 6;           // wave = unit-block 0..4
  const int l   = tid & 63;
  const int lr  = l & 15;             // frag row; C' col = seq
  const int q   = l >> 4;             // k-octet; C' row-block
  const int u   = 16 * w + lr;        // weight-fragment unit
  const int ub4 = 16 * w + 4 * q;     // first of lane's 4 output units
  const int p   = blockIdx.x >> 1;
  const int role = blockIdx.x & 1;

  int* prog0p = prog0 + p;
  int* prog1p = prog1 + p;
  char* ringp = ring + (size_t)p * (RING_D * RSLOT);

  if (tid < NB) {
    int pb = perm[p * NB + tid];
    pbs[tid] = pb;
    lns[tid] = slen[pb];
  }

  if (role == 0) {
    // ================= LAYER-0 PRODUCER =================
    bf16x8 wf[4][KS0];
    float  bias[4][4];
    #pragma unroll
    for (int g = 0; g < 4; ++g) {
      const float sc = (g == 2) ? K2 : LOG2E;
      const int n = 80 * g + u;
      #pragma unroll
      for (int r = 0; r < 4; ++r) {
        const int nb = 80 * g + ub4 + r;
        bias[g][r] = (bih0[nb] + bhh0[nb]) * sc;
      }
      #pragma unroll
      for (int ks = 0; ks < KS0; ++ks) {
        bf16x8 vv;
        #pragma unroll
        for (int j = 0; j < 8; ++j) {
          int k = 32 * ks + 8 * q + j;
          float f = (k < 8)  ? Wih0[n * D_ + k]
                  : (k < 16) ? Wih0[n * D_ + (k - 8)]
                             : Whh0[n * H_ + (k - 16)];
          vv[j] = (short)f2bf(f * sc);
        }
        wf[g][ks] = vv;
      }
    }
    for (int i = tid; i < (2 * A0BUF) / 4; i += NTH) ((int*)lds)[i] = 0;
    __syncthreads();
    const int mlen = lns[0];

    // x machinery (waves 0-3): lane owns x[xs][chunkbase+xt][4xh..+4)
    const int xs = tid >> 4, xt = (tid & 15) >> 1, xh = tid & 1;
    const float* xbase = nullptr;
    f32x4 xa = {}, xb = {};
    if (tid < 256) {
      xbase = X + (size_t)pbs[xs] * (T_ * D_) + 4 * xh;
      int t0 = xt;     if (t0 > T_ - 1) t0 = T_ - 1;
      int t1 = 8 + xt; if (t1 > T_ - 1) t1 = T_ - 1;
      xa = *(const f32x4*)(xbase + t0 * D_);
      xb = *(const f32x4*)(xbase + t1 * D_);
    }
    if (tid < 256 && xt == 0) {         // stage x(0) -> A0[0]
      u16x4 hi, lo;
      #pragma unroll
      for (int j = 0; j < 4; ++j) { hi[j] = f2bf(xa[j]); lo[j] = f2bf(xa[j] - bf2f(hi[j])); }
      *(u16x4*)(lds + xs * A0S + swz(xs, 8 * xh))      = hi;
      *(u16x4*)(lds + xs * A0S + swz(xs, 16 + 8 * xh)) = lo;
    }
    __syncthreads();

    float c[4] = {0.f, 0.f, 0.f, 0.f};
    int p1c = 0;

    #pragma unroll 2
    for (int i = 0; i < mlen; ++i) {
      if (tid == 0)                      // h0(0..i-1) published (drained at prior barrier)
        __hip_atomic_store(prog0p, i, __ATOMIC_RELEASE, __HIP_MEMORY_SCOPE_AGENT);
      if ((i & 7) == 0 && i >= 16) {     // ring space for steps i..i+7
        const int target = i - 8;
        if (p1c < target) {
          int pv;
          do {
            pv = __hip_atomic_load(prog1p, __ATOMIC_ACQUIRE, __HIP_MEMORY_SCOPE_AGENT);
            if (pv < target) __builtin_amdgcn_s_sleep(4);
          } while (pv < target);
          p1c = pv;
        }
      }
      if (tid < 256 && ((i + 1) & 7) == 0) {   // rotate x chunk regs
        xa = xb;
        int tc = i + 9 + xt; if (tc > T_ - 1) tc = T_ - 1;
        xb = *(const f32x4*)(xbase + tc * D_);
      }

      const char* A0p = lds + (i & 1) * A0BUF;
      f32x4 acc[4] = {};
      #pragma unroll
      for (int ks = 0; ks < KS0; ++ks) {
        bf16x8 a = *(const bf16x8*)(A0p + lr * A0S + swz(lr, 64 * ks + 16 * q));
        #pragma unroll
        for (int g = 0; g < 4; ++g)
          acc[g] = __builtin_amdgcn_mfma_f32_16x16x32_bf16(wf[g][ks], a, acc[g], 0, 0, 0);
      }

      char* A0n = lds + ((i + 1) & 1) * A0BUF;
      if (tid < 256 && xt == ((i + 1) & 7)) {  // stage x(i+1) -> A0 next
        u16x4 hi, lo;
        #pragma unroll
        for (int j = 0; j < 4; ++j) { hi[j] = f2bf(xa[j]); lo[j] = f2bf(xa[j] - bf2f(hi[j])); }
        *(u16x4*)(A0n + xs * A0S + swz(xs, 8 * xh))      = hi;
        *(u16x4*)(A0n + xs * A0S + swz(xs, 16 + 8 * xh)) = lo;
      }

      u16x4 hv;
      #pragma unroll
      for (int r = 0; r < 4; ++r) {
        float h = cell(acc[0][r] + bias[0][r], acc[1][r] + bias[1][r],
                       acc[2][r] + bias[2][r], acc[3][r] + bias[3][r], c[r]);
        hv[r] = f2bf(h);
      }
      *(u16x4*)(A0n + lr * A0S + swz(lr, 32 + 2 * ub4)) = hv;   // own recurrence
      __hip_atomic_store((u64*)(ringp + (size_t)(i & (RING_D - 1)) * RSLOT
                                + lr * 160 + 2 * ub4),
                         __builtin_bit_cast(u64, hv),
                         __ATOMIC_RELAXED, __HIP_MEMORY_SCOPE_AGENT);
      __syncthreads();                   // drains ring store (vmcnt) + LDS
    }
    if (tid == 0)
      __hip_atomic_store(prog0p, mlen, __ATOMIC_RELEASE, __HIP_MEMORY_SCOPE_AGENT);

  } else {
    // ================= LAYER-1 CONSUMER =================
    bf16x8 wf[4][KS1];
    float  bias[4][4];
    #pragma unroll
    for (int g = 0; g < 4; ++g) {
      const float sc = (g == 2) ? K2 : LOG2E;
      const int n = 80 * g + u;
      #pragma unroll
      for (int r = 0; r < 4; ++r) {
        const int nb = 80 * g + ub4 + r;
        bias[g][r] = (bih1[nb] + bhh1[nb]) * sc;
      }
      #pragma unroll
      for (int ks = 0; ks < KS1; ++ks) {
        bf16x8 vv;
        #pragma unroll
        for (int j = 0; j < 8; ++j) {
          int k = 32 * ks + 8 * q + j;
          float f = (k < 80) ? Wih1[n * H_ + k] : Whh1[n * H_ + (k - 80)];
          vv[j] = (short)f2bf(f * sc);
        }
        wf[g][ks] = vv;
      }
    }
    for (int i = tid; i < (2 * A1BUF) / 4; i += NTH) ((int*)lds)[i] = 0;
    __syncthreads();
    const int mlen  = lns[0];
    const int pbseq = pbs[lr];
    const int lm1   = lns[lr] - 1;

    const int ss = tid / 20, qd = tid - (tid / 20) * 20;  // staging map: 8B each
    int p0c = 0;
    {
      const int target = (mlen < 5) ? mlen : 5;
      int pv;
      do {
        pv = __hip_atomic_load(prog0p, __ATOMIC_ACQUIRE, __HIP_MEMORY_SCOPE_AGENT);
        if (pv < target) __builtin_amdgcn_s_sleep(4);
      } while (pv < target);
      p0c = pv;
    }
    {   // stage ring slot 0 -> A1[0] h0-region
      u64 v0 = __hip_atomic_load((const u64*)(ringp + ss * 160 + qd * 8),
                                 __ATOMIC_RELAXED, __HIP_MEMORY_SCOPE_AGENT);
      *(u64*)(lds + ss * A1S + swz(ss, qd * 8)) = v0;
    }
    __syncthreads();

    float c[4] = {0.f, 0.f, 0.f, 0.f};

    #pragma unroll 2
    for (int i = 0; i < mlen; ++i) {
      if ((i & 3) == 0) {
        if (tid == 0)
          __hip_atomic_store(prog1p, i, __ATOMIC_RELAXED, __HIP_MEMORY_SCOPE_AGENT);
        int target = i + 5; if (target > mlen) target = mlen;
        if (p0c < target) {
          int pv;
          do {
            pv = __hip_atomic_load(prog0p, __ATOMIC_ACQUIRE, __HIP_MEMORY_SCOPE_AGENT);
            if (pv < target) __builtin_amdgcn_s_sleep(4);
          } while (pv < target);
          p0c = pv;
        }
      }
      const bool pf = (i + 1 < mlen);
      u64 vst = 0;
      if (pf)                              // prefetch h0(i+1) (T14: issue early)
        vst = __hip_atomic_load((const u64*)(ringp
                + (size_t)((i + 1) & (RING_D - 1)) * RSLOT + ss * 160 + qd * 8),
                __ATOMIC_RELAXED, __HIP_MEMORY_SCOPE_AGENT);

      const char* A1p = lds + (i & 1) * A1BUF;
      f32x4 acc[4] = {};
      #pragma unroll
      for (int ks = 0; ks < KS1; ++ks) {
        bf16x8 a = *(const bf16x8*)(A1p + lr * A1S + swz(lr, 64 * ks + 16 * q));
        #pragma unroll
        for (int g = 0; g < 4; ++g)
          acc[g] = __builtin_amdgcn_mfma_f32_16x16x32_bf16(wf[g][ks], a, acc[g], 0, 0, 0);
      }

      char* A1n = lds + ((i + 1) & 1) * A1BUF;
      float h[4];
      u16x4 hv;
      #pragma unroll
      for (int r = 0; r < 4; ++r) {
        h[r] = cell(acc[0][r] + bias[0][r], acc[1][r] + bias[1][r],
                    acc[2][r] + bias[2][r], acc[3][r] + bias[3][r], c[r]);
        hv[r] = f2bf(h[r]);
      }
      *(u16x4*)(A1n + lr * A1S + swz(lr, 160 + 2 * ub4)) = hv;   // h1 self
      if (pf)                              // write-late staged h0(i+1)
        *(u64*)(A1n + ss * A1S + swz(ss, qd * 8)) = vst;
      if (i == lm1)
        *(f32x4*)(out + (size_t)pbseq * H_ + ub4) = (f32x4){h[0], h[1], h[2], h[3]};
      __syncthreads();
    }
    if (tid == 0)
      __hip_atomic_store(prog1p, mlen, __ATOMIC_RELAXED, __HIP_MEMORY_SCOPE_AGENT);
  }
}

extern "C" void kernel_launch(void* const* d_in, const int* in_sizes, int n_in,
                              void* d_out, int out_size, void* d_ws, size_t ws_size,
                              hipStream_t stream) {
  const float* X    = (const float*)d_in[0];
  const float* Wih0 = (const float*)d_in[1];
  const float* Whh0 = (const float*)d_in[2];
  const float* bih0 = (const float*)d_in[3];
  const float* bhh0 = (const float*)d_in[4];
  const float* Wih1 = (const float*)d_in[5];
  const float* Whh1 = (const float*)d_in[6];
  const float* bih1 = (const float*)d_in[7];
  const float* bhh1 = (const float*)d_in[8];
  const int*   slen = (const int*)d_in[9];

  int*  perm  = (int*)d_ws;                       // [0, 8192)
  int*  flags = (int*)((char*)d_ws + 8192);       // prog0[128] ++ prog1[128]
  int*  prog0 = flags;
  int*  prog1 = flags + 128;
  char* ring  = (char*)d_ws + 16384;              // 128 pairs x 16 x 2560 B ~ 5.25 MB

  sort_by_len<<<1, 512, 0, stream>>>(slen, perm, flags);
  lstm2_pc<<<2 * NPAIR, NTH, 0, stream>>>(
      X, Wih0, Whh0, bih0, bhh0, Wih1, Whh1, bih1, bhh1, slen, perm,
      prog0, prog1, ring, (float*)d_out);
}

// Round 13
// 598.513 us; speedup vs baseline: 1.9458x; 1.9458x over previous
//
#include <hip/hip_runtime.h>
#include <math.h>

#define B_   2048
#define T_   512
#define D_   8
#define H_   80
#define NB   16
#define NBLK (B_ / NB)     // 128 blocks
#define NTH  640           // 10 waves: (layer L in {0,1}) x (unit-block v in 0..4)
#define KS0  3             // A0: K=96  = [x_hi(8) | x_lo(8) | h0(80)]
#define KS1  5             // A1: K=160 = [h0(80) | h1(80)]
#define A0S  256           // A0 row stride bytes (128 bf16)
#define A1S  384           // A1 row stride bytes (192 bf16)
#define A0BUF (16 * A0S)   // 4 KB
#define A1BUF (16 * A1S)   // 6 KB
#define LOG2E 1.44269504f
#define K2    2.88539008f  // 2*log2(e)

typedef float f32x4  __attribute__((ext_vector_type(4)));
typedef short bf16x8 __attribute__((ext_vector_type(8)));
typedef unsigned short u16x4 __attribute__((ext_vector_type(4)));

__device__ __forceinline__ float E2(float x) {
#if __has_builtin(__builtin_amdgcn_exp2f)
  return __builtin_amdgcn_exp2f(x);
#else
  return __expf(x * 0.6931471806f);   // exp(x*ln2) = 2^x
#endif
}
__device__ __forceinline__ unsigned short f2bf(float f) {  // RNE f32->bf16
  unsigned u = __builtin_bit_cast(unsigned, f);
  return (unsigned short)((u + 0x7FFFu + ((u >> 16) & 1u)) >> 16);
}
__device__ __forceinline__ float bf2f(unsigned short b) {
  unsigned u = ((unsigned)b) << 16;
  return __builtin_bit_cast(float, u);
}
__device__ __forceinline__ int swz(int row, int byte_in_row) {
  return byte_in_row ^ ((row & 7) << 4);
}
// LSTM cell, gates PRESCALED: ai,af,ao by log2e; ag by 2*log2e. c true-domain.
// sigm(x)=rcp(1+2^-x'); tanh fused with its sigmoid partner via shared rcp.
// Overflow-safe: tanh(c) via |c| (ec<=1); products bounded < 2^105 for
// |gate|<=~20 (holds for U(-1/sqrt(80)) weights, N(0,1) x, |h|<=1).
__device__ __forceinline__ float cell(float ai, float af, float ag, float ao,
                                      float& c) {
  const float ei = E2(-ai), ef = E2(-af), eg = E2(-ag), eo = E2(-ao);
  const float P  = (1.0f + ei) * (1.0f + eg);
  const float pf = 1.0f + ef;
  const float cn = __builtin_fmaf(c, P, (1.0f - eg) * pf)
                 * __builtin_amdgcn_rcpf(P * pf);
  c = cn;
  const float ec = E2(-K2 * fabsf(cn));
  const float t  = (1.0f - ec)
                 * __builtin_amdgcn_rcpf((1.0f + eo) * (1.0f + ec));
  return copysignf(t, cn);
}

// ---- counting sort by length, DESCENDING ----
__global__ __launch_bounds__(512)
void sort_by_len(const int* __restrict__ slen, int* __restrict__ perm) {
  __shared__ int cnt[513];
  const int tid = threadIdx.x;
  for (int i = tid; i < 513; i += 512) cnt[i] = 0;
  __syncthreads();
  for (int b = tid; b < B_; b += 512) atomicAdd(&cnt[T_ - slen[b]], 1);
  __syncthreads();
  if (tid == 0) { int s = 0;
    for (int k = 0; k < 513; ++k) { int c = cnt[k]; cnt[k] = s; s += c; } }
  __syncthreads();
  for (int b = tid; b < B_; b += 512) {
    int pos = atomicAdd(&cnt[T_ - slen[b]], 1);
    perm[pos] = b;   // equal-length order arbitrary: per-seq results independent
  }
}

// ---- fused 2-layer LSTM: 10 waves, wave = (layer, 16-unit block) ----
// OPERAND-SWAPPED MFMA: C' = W (A-op) x act^T (B-op). Fragment register
// contents identical to the old orientation (A/B layouts are symmetric);
// C' layout: col(lane&15)=seq, row(4q+reg)=unit -> lane owns 4 CONSECUTIVE
// units of ONE seq => packed b64 h-writes and dwordx4 output store.
// Skew: interval i = L1(i) || L0(i+1); ONE barrier per interval.
__global__ __launch_bounds__(NTH)
void lstm2_mfma(const float* __restrict__ X,
                const float* __restrict__ Wih0, const float* __restrict__ Whh0,
                const float* __restrict__ bih0, const float* __restrict__ bhh0,
                const float* __restrict__ Wih1, const float* __restrict__ Whh1,
                const float* __restrict__ bih1, const float* __restrict__ bhh1,
                const int* __restrict__ slen, const int* __restrict__ perm,
                float* __restrict__ out)
{
  __shared__ char a0lds[2 * A0BUF];
  __shared__ char a1lds[2 * A1BUF];
  __shared__ int  pbs[NB];
  __shared__ int  lns[NB];

  const int tid = threadIdx.x;
  const int w   = tid >> 6;
  const int l   = tid & 63;
  const int lr  = l & 15;           // frag row/col; C' col = seq
  const int q   = l >> 4;           // k-octet; C' row-block (units 4q..4q+3)
  const int L   = (w < 5) ? 0 : 1;  // layer
  const int v   = w - 5 * L;        // unit-block 0..4
  const int u   = 16 * v + lr;      // weight-fragment unit (frag row)
  const int ub4 = 16 * v + 4 * q;   // first of this lane's 4 output units

  if (tid < NB) {
    int pb = perm[blockIdx.x * NB + tid];
    pbs[tid] = pb;
    lns[tid] = slen[pb];
  }

  // ---- weight fragments (PRESCALED): tile g = gate g, units 16v..16v+15 ----
  // frag: lane row u=16v+lr, elem j <-> k = 32*ks + 8*q + j. Same registers
  // as the unswapped orientation.
  bf16x8 wf[4][KS1];
  float  bias[4][4];                // [gate][r] for unit ub4+r
  if (L == 0) {
    #pragma unroll
    for (int g = 0; g < 4; ++g) {
      const float sc = (g == 2) ? K2 : LOG2E;
      const int n = 80 * g + u;
      #pragma unroll
      for (int r = 0; r < 4; ++r) {
        const int nb = 80 * g + ub4 + r;
        bias[g][r] = (bih0[nb] + bhh0[nb]) * sc;
      }
      #pragma unroll
      for (int ks = 0; ks < KS0; ++ks) {
        bf16x8 vv;
        #pragma unroll
        for (int j = 0; j < 8; ++j) {
          int k = 32 * ks + 8 * q + j;
          float f = (k < 8)  ? Wih0[n * D_ + k]
                  : (k < 16) ? Wih0[n * D_ + (k - 8)]
                             : Whh0[n * H_ + (k - 16)];
          vv[j] = (short)f2bf(f * sc);
        }
        wf[g][ks] = vv;
      }
    }
  } else {
    #pragma unroll
    for (int g = 0; g < 4; ++g) {
      const float sc = (g == 2) ? K2 : LOG2E;
      const int n = 80 * g + u;
      #pragma unroll
      for (int r = 0; r < 4; ++r) {
        const int nb = 80 * g + ub4 + r;
        bias[g][r] = (bih1[nb] + bhh1[nb]) * sc;
      }
      #pragma unroll
      for (int ks = 0; ks < KS1; ++ks) {
        bf16x8 vv;
        #pragma unroll
        for (int j = 0; j < 8; ++j) {
          int k = 32 * ks + 8 * q + j;
          float f = (k < 80) ? Wih1[n * H_ + k] : Whh1[n * H_ + (k - 80)];
          vv[j] = (short)f2bf(f * sc);
        }
        wf[g][ks] = vv;
      }
    }
  }

  for (int i = tid; i < (2 * A0BUF) / 4; i += NTH) ((int*)a0lds)[i] = 0;
  for (int i = tid; i < (2 * A1BUF) / 4; i += NTH) ((int*)a1lds)[i] = 0;
  __syncthreads();                      // pbs/lns + zeros visible

  const int mlen  = lns[0];
  const int pbseq = pbs[lr];            // this lane's seq (C' col)
  const int lm1   = lns[lr] - 1;

  // ---- x machinery (waves 0-3, all L0): lane owns x[xs][chunk+xt][4xh..+4) ----
  const int xs = tid >> 4, xt = (tid & 15) >> 1, xh = tid & 1;
  const float* xbase = nullptr;
  f32x4 xa = {}, xb = {};
  if (tid < 256) {
    xbase = X + (size_t)pbs[xs] * (T_ * D_) + 4 * xh;
    int t0 = xt;     if (t0 > T_ - 1) t0 = T_ - 1;
    int t1 = 8 + xt; if (t1 > T_ - 1) t1 = T_ - 1;
    xa = *(const f32x4*)(xbase + t0 * D_);
    xb = *(const f32x4*)(xbase + t1 * D_);
  }
  #pragma unroll
  for (int tt = 0; tt < 2; ++tt) {
    if (tid < 256 && xt == tt) {
      u16x4 hi, lo;
      #pragma unroll
      for (int j = 0; j < 4; ++j) { hi[j] = f2bf(xa[j]); lo[j] = f2bf(xa[j] - bf2f(hi[j])); }
      char* buf = a0lds + tt * A0BUF;
      *(u16x4*)(buf + xs * A0S + swz(xs, 8 * xh))      = hi;
      *(u16x4*)(buf + xs * A0S + swz(xs, 16 + 8 * xh)) = lo;
    }
  }
  __syncthreads();                      // x(0), x(1) visible

  float c[4] = {0.f, 0.f, 0.f, 0.f};    // state for (unit ub4+r, seq lr)

  // ---- prologue: L0(0) on L0 waves ----
  if (L == 0) {
    f32x4 acc[4] = {};
    #pragma unroll
    for (int ks = 0; ks < KS0; ++ks) {
      bf16x8 a = *(const bf16x8*)(a0lds + lr * A0S + swz(lr, 64 * ks + 16 * q));
      #pragma unroll
      for (int g = 0; g < 4; ++g)
        acc[g] = __builtin_amdgcn_mfma_f32_16x16x32_bf16(wf[g][ks], a, acc[g], 0, 0, 0);
    }
    char* A1w = a1lds;                  // A1[0] h0-region
    char* A0w = a0lds + A0BUF;          // A0[1] h0-region
    u16x4 hv;
    #pragma unroll
    for (int r = 0; r < 4; ++r) {
      float h = cell(acc[0][r] + bias[0][r], acc[1][r] + bias[1][r],
                     acc[2][r] + bias[2][r], acc[3][r] + bias[3][r], c[r]);
      hv[r] = f2bf(h);
    }
    *(u16x4*)(A1w + lr * A1S + swz(lr, 2 * ub4))      = hv;
    *(u16x4*)(A0w + lr * A0S + swz(lr, 32 + 2 * ub4)) = hv;
  }
  __syncthreads();                      // h0(0), x(1) visible

  // ---- main loop: interval i = { L1(i) || L0(i+1) }, ONE barrier ----
  #pragma unroll 2
  for (int i = 0; i < mlen; ++i) {
    const int cur = i & 1, nxt = cur ^ 1;

    if (tid < 256 && ((i + 2) & 7) == 0) {          // rotate x chunk regs
      xa = xb;
      int tc = i + 10 + xt; if (tc > T_ - 1) tc = T_ - 1;
      xb = *(const f32x4*)(xbase + tc * D_);
    }

    f32x4 acc[4] = {};
    if (L == 1) {
      const char* A1p = a1lds + cur * A1BUF;        // L1(i) input [h0(i)|h1(i-1)]
      #pragma unroll
      for (int ks = 0; ks < KS1; ++ks) {
        bf16x8 a = *(const bf16x8*)(A1p + lr * A1S + swz(lr, 64 * ks + 16 * q));
        #pragma unroll
        for (int g = 0; g < 4; ++g)
          acc[g] = __builtin_amdgcn_mfma_f32_16x16x32_bf16(wf[g][ks], a, acc[g], 0, 0, 0);
      }
    } else {
      const char* A0p = a0lds + nxt * A0BUF;        // L0(i+1) input [x(i+1)|h0(i)]
      #pragma unroll
      for (int ks = 0; ks < KS0; ++ks) {
        bf16x8 a = *(const bf16x8*)(A0p + lr * A0S + swz(lr, 64 * ks + 16 * q));
        #pragma unroll
        for (int g = 0; g < 4; ++g)
          acc[g] = __builtin_amdgcn_mfma_f32_16x16x32_bf16(wf[g][ks], a, acc[g], 0, 0, 0);
      }
    }

    if (tid < 256 && xt == ((i + 2) & 7)) {          // stage x(i+2) -> A0[cur]
      u16x4 hi, lo;
      #pragma unroll
      for (int j = 0; j < 4; ++j) { hi[j] = f2bf(xa[j]); lo[j] = f2bf(xa[j] - bf2f(hi[j])); }
      char* buf = a0lds + cur * A0BUF;
      *(u16x4*)(buf + xs * A0S + swz(xs, 8 * xh))      = hi;
      *(u16x4*)(buf + xs * A0S + swz(xs, 16 + 8 * xh)) = lo;
    }

    char* A1n = a1lds + nxt * A1BUF;
    char* A0c = a0lds + cur * A0BUF;

    if (L == 1) {                        // L1(i) cells + packed writes + output
      float h[4];
      u16x4 hv;
      #pragma unroll
      for (int r = 0; r < 4; ++r) {
        h[r] = cell(acc[0][r] + bias[0][r], acc[1][r] + bias[1][r],
                    acc[2][r] + bias[2][r], acc[3][r] + bias[3][r], c[r]);
        hv[r] = f2bf(h[r]);
      }
      *(u16x4*)(A1n + lr * A1S + swz(lr, 160 + 2 * ub4)) = hv;
      if (i == lm1)
        *(f32x4*)(out + (size_t)pbseq * H_ + ub4) = (f32x4){h[0], h[1], h[2], h[3]};
    } else {                             // L0(i+1) cells + packed writes
      u16x4 hv;
      #pragma unroll
      for (int r = 0; r < 4; ++r) {
        float h = cell(acc[0][r] + bias[0][r], acc[1][r] + bias[1][r],
                       acc[2][r] + bias[2][r], acc[3][r] + bias[3][r], c[r]);
        hv[r] = f2bf(h);
      }
      *(u16x4*)(A1n + lr * A1S + swz(lr, 2 * ub4))      = hv;
      *(u16x4*)(A0c + lr * A0S + swz(lr, 32 + 2 * ub4)) = hv;
    }
    __syncthreads();
  }
}

extern "C" void kernel_launch(void* const* d_in, const int* in_sizes, int n_in,
                              void* d_out, int out_size, void* d_ws, size_t ws_size,
                              hipStream_t stream) {
  const float* X    = (const float*)d_in[0];
  const float* Wih0 = (const float*)d_in[1];
  const float* Whh0 = (const float*)d_in[2];
  const float* bih0 = (const float*)d_in[3];
  const float* bhh0 = (const float*)d_in[4];
  const float* Wih1 = (const float*)d_in[5];
  const float* Whh1 = (const float*)d_in[6];
  const float* bih1 = (const float*)d_in[7];
  const float* bhh1 = (const float*)d_in[8];
  const int*   slen = (const int*)d_in[9];
  int* perm = (int*)d_ws;   // 2048 ints

  sort_by_len<<<1, 512, 0, stream>>>(slen, perm);
  lstm2_mfma<<<NBLK, NTH, 0, stream>>>(
      X, Wih0, Whh0, bih0, bhh0, Wih1, Whh1, bih1, bhh1, slen, perm,
      (float*)d_out);
}